// Round 2
// baseline (155.689 us; speedup 1.0000x reference)
//
#include <hip/hip_runtime.h>

// Problem constants
#define N_   8
#define C_   32
#define H_   256
#define W_   256
#define HW_  (H_ * W_)

// ---------------------------------------------------------------------------
// Kernel 1: per-(n,c) instance-norm stats folded with gamma/beta into
//           scale/shift:  xn = x*scale + shift
// grid = 256 (one wg per (n,c) plane), block = 1024 (16 waves -> 4/SIMD)
// fp32 per-lane accumulators (16 terms each, rel err ~1e-6), fp64 reduce.
// ---------------------------------------------------------------------------
__global__ __launch_bounds__(1024) void stats_kernel(
    const float* __restrict__ x, const float* __restrict__ gamma,
    const float* __restrict__ beta, float2* __restrict__ ss)
{
    const int nc = blockIdx.x;      // n*32 + c
    const int t  = threadIdx.x;
    const float4* p = (const float4*)(x + (size_t)nc * HW_);

    float s0 = 0.f, s1 = 0.f, s2 = 0.f, s3 = 0.f;
    float q0 = 0.f, q1 = 0.f, q2 = 0.f, q3 = 0.f;
    #pragma unroll
    for (int i = 0; i < 16; ++i) {
        float4 v = p[t + (i << 10)];
        s0 += v.x; s1 += v.y; s2 += v.z; s3 += v.w;
        q0 = fmaf(v.x, v.x, q0); q1 = fmaf(v.y, v.y, q1);
        q2 = fmaf(v.z, v.z, q2); q3 = fmaf(v.w, v.w, q3);
    }
    double s = (double)s0 + (double)s1 + (double)s2 + (double)s3;
    double q = (double)q0 + (double)q1 + (double)q2 + (double)q3;
    #pragma unroll
    for (int off = 32; off > 0; off >>= 1) {
        s += __shfl_down(s, off);
        q += __shfl_down(q, off);
    }
    __shared__ double rs[16], rq[16];
    const int wid = t >> 6;
    if ((t & 63) == 0) { rs[wid] = s; rq[wid] = q; }
    __syncthreads();
    if (t == 0) {
        double S = 0.0, Q = 0.0;
        #pragma unroll
        for (int i = 0; i < 16; ++i) { S += rs[i]; Q += rq[i]; }
        double mean = S / (double)HW_;
        double var  = Q / (double)HW_ - mean * mean;
        double grs  = (double)gamma[nc & (C_ - 1)] / sqrt(var + 1e-5);
        float scale = (float)grs;
        float shift = (float)((double)beta[nc & (C_ - 1)] - mean * grs);
        ss[nc] = make_float2(scale, shift);
    }
}

// ---------------------------------------------------------------------------
// Kernel 2: fused  normalize -> pooled sparse field -> 1x1 conv -> relu
//
// For each 2x2 spatial pooling block (h-blocks align to even h; w-blocks
// cover {2j-1,2j}), m = max of the 4 normalized values (pads = 0), s* =
// first argmax in (r,kw) order:
//   m > 0  -> 0.75*m at s*  (depths 1,2,4 survive crop, /4 depth-mean)
//   m <= 0 -> 0.25*m at s*  (middle depth block only), 0 if s* is a pad.
// Then out[n,o] = relu(b[o] + sum_c W[o,c] * collapsed[n,c]).
//
// grid = (128 h-pairs, 8 n), block = 512 (8 waves)
// ---------------------------------------------------------------------------
__global__ __launch_bounds__(512) void fused_kernel(
    const float* __restrict__ x, const float2* __restrict__ ss,
    const float* __restrict__ Wm, const float* __restrict__ bias,
    float* __restrict__ out)
{
    const int k = blockIdx.x;   // h-pair: rows 2k, 2k+1
    const int n = blockIdx.y;
    const int t = threadIdx.x;

    __shared__ float         sWT[C_][C_];  // sWT[c][o] = W[o,c]
    __shared__ float         sE[C_][66];   // even-j block values, idx j/2 (0..64)
    __shared__ float         sO[C_][64];   // odd-j block values, idx j>>1
    __shared__ unsigned char pE[C_][66];   // argmax pos 0..3
    __shared__ unsigned char pO[C_][64];

    // stage W^T (Wm is [o][c] row-major)
    {
        int i = t;
        #pragma unroll
        for (int r = 0; r < 2; ++r, i += 512) {
            int o = i >> 5, c = i & 31;
            sWT[c][o] = Wm[i];
        }
    }

    // ---- Phase A: vectorized loads + per-block max/argmax ------------------
    // thread owns 16 contiguous columns [16*li, 16*li+16) of channel c, both rows
    const int c  = t >> 4;
    const int li = t & 15;
    const float2 sc = ss[n * C_ + c];
    const float* r0p = x + (size_t)(n * C_ + c) * HW_
                         + (size_t)(2 * k) * W_ + 16 * li;
    const float* r1p = r0p + W_;

    float4 u0[4], u1[4];
    #pragma unroll
    for (int q = 0; q < 4; ++q) u0[q] = ((const float4*)r0p)[q];
    #pragma unroll
    for (int q = 0; q < 4; ++q) u1[q] = ((const float4*)r1p)[q];

    // vertical max + argmax-row bitmask (tie -> row 0 = smaller position)
    float vm[16];
    unsigned vr = 0;
    #pragma unroll
    for (int q = 0; q < 4; ++q) {
        float a0, a1;
        a0 = fmaf(u0[q].x, sc.x, sc.y); a1 = fmaf(u1[q].x, sc.x, sc.y);
        vm[4*q+0] = fmaxf(a0, a1); if (a1 > a0) vr |= 1u << (4*q+0);
        a0 = fmaf(u0[q].y, sc.x, sc.y); a1 = fmaf(u1[q].y, sc.x, sc.y);
        vm[4*q+1] = fmaxf(a0, a1); if (a1 > a0) vr |= 1u << (4*q+1);
        a0 = fmaf(u0[q].z, sc.x, sc.y); a1 = fmaf(u1[q].z, sc.x, sc.y);
        vm[4*q+2] = fmaxf(a0, a1); if (a1 > a0) vr |= 1u << (4*q+2);
        a0 = fmaf(u0[q].w, sc.x, sc.y); a1 = fmaf(u1[q].w, sc.x, sc.y);
        vm[4*q+3] = fmaxf(a0, a1); if (a1 > a0) vr |= 1u << (4*q+3);
    }

    // left-neighbor column (w = 16*li - 1) via shfl within the wave
    const float    vmL = __shfl_up(vm[15], 1);
    const unsigned vrL = __shfl_up(vr, 1);
    const int      rLn = (int)((vrL >> 15) & 1u);

    // blocks j = 8*li + b ; colL = w 2j-1, colR = w 2j
    #pragma unroll
    for (int b = 0; b < 8; ++b) {
        float vL; int rL; bool padL;
        if (b == 0) {
            padL = (li == 0);
            vL = padL ? 0.f : vmL;
            rL = padL ? 0   : rLn;
        } else {
            vL = vm[2*b - 1]; rL = (int)((vr >> (2*b - 1)) & 1u); padL = false;
        }
        float vR = vm[2*b]; int rR = (int)((vr >> (2*b)) & 1u);
        // choose colL iff strictly larger, or equal with smaller position code
        bool chooseL = (vL > vR) || ((vL == vR) && (rL <= rR));
        float m   = chooseL ? vL : vR;
        int   p   = chooseL ? (rL << 1) : ((rR << 1) | 1);
        float val = m * (m > 0.f ? 0.75f : 0.25f);
        if (chooseL && padL) val = 0.f;   // argmax at left spatial pad
        int j = 8 * li + b;
        if (b & 1) { sO[c][j >> 1] = val; pO[c][j >> 1] = (unsigned char)p; }
        else       { sE[c][j >> 1] = val; pE[c][j >> 1] = (unsigned char)p; }
    }
    if (li == 15) {   // block j = 128: colL = w 255, colR = right pad
        float vL = vm[15]; int rL = (int)((vr >> 15) & 1u);
        bool chooseL = (vL > 0.f) || ((vL == 0.f) && (rL <= 0));
        float m   = chooseL ? vL : 0.f;
        int   p   = chooseL ? (rL << 1) : 1;
        float val = m * (m > 0.f ? 0.75f : 0.25f);
        if (!chooseL) val = 0.f;          // argmax at right spatial pad
        sE[c][64] = val; pE[c][64] = (unsigned char)p;
    }
    __syncthreads();

    // ---- Phase B: gather + 32x32 channel mix (wave owns 4 out-channels) ----
    const int wv = t >> 6;        // wave 0..7
    const int ob = wv << 2;       // out-channel base
    const int wt = t & 63;        // lane owns columns 4wt..4wt+3

    float acc[2][4][4];           // [row][dw][oo]
    #pragma unroll
    for (int oo = 0; oo < 4; ++oo) {
        float bo = bias[ob + oo];
        #pragma unroll
        for (int r = 0; r < 2; ++r)
            #pragma unroll
            for (int dw = 0; dw < 4; ++dw) acc[r][dw][oo] = bo;
    }

    // lane columns: dw0 -> (E[wt], kw1) ; dw1 -> (O[wt], kw0) ;
    //               dw2 -> (O[wt], kw1) ; dw3 -> (E[wt+1], kw0)
    for (int cc = 0; cc < C_; ++cc) {
        float w0 = sWT[cc][ob + 0], w1 = sWT[cc][ob + 1];
        float w2 = sWT[cc][ob + 2], w3 = sWT[cc][ob + 3];
        float vA = sE[cc][wt];     int pA = pE[cc][wt];
        float vB = sO[cc][wt];     int pB = pO[cc][wt];
        float vC = sE[cc][wt + 1]; int pC = pE[cc][wt + 1];
        float m00 = (pA == 1) ? vA : 0.f, m10 = (pA == 3) ? vA : 0.f;
        float m01 = (pB == 0) ? vB : 0.f, m11 = (pB == 2) ? vB : 0.f;
        float m02 = (pB == 1) ? vB : 0.f, m12 = (pB == 3) ? vB : 0.f;
        float m03 = (pC == 0) ? vC : 0.f, m13 = (pC == 2) ? vC : 0.f;
        acc[0][0][0] = fmaf(m00, w0, acc[0][0][0]);
        acc[0][1][0] = fmaf(m01, w0, acc[0][1][0]);
        acc[0][2][0] = fmaf(m02, w0, acc[0][2][0]);
        acc[0][3][0] = fmaf(m03, w0, acc[0][3][0]);
        acc[1][0][0] = fmaf(m10, w0, acc[1][0][0]);
        acc[1][1][0] = fmaf(m11, w0, acc[1][1][0]);
        acc[1][2][0] = fmaf(m12, w0, acc[1][2][0]);
        acc[1][3][0] = fmaf(m13, w0, acc[1][3][0]);
        acc[0][0][1] = fmaf(m00, w1, acc[0][0][1]);
        acc[0][1][1] = fmaf(m01, w1, acc[0][1][1]);
        acc[0][2][1] = fmaf(m02, w1, acc[0][2][1]);
        acc[0][3][1] = fmaf(m03, w1, acc[0][3][1]);
        acc[1][0][1] = fmaf(m10, w1, acc[1][0][1]);
        acc[1][1][1] = fmaf(m11, w1, acc[1][1][1]);
        acc[1][2][1] = fmaf(m12, w1, acc[1][2][1]);
        acc[1][3][1] = fmaf(m13, w1, acc[1][3][1]);
        acc[0][0][2] = fmaf(m00, w2, acc[0][0][2]);
        acc[0][1][2] = fmaf(m01, w2, acc[0][1][2]);
        acc[0][2][2] = fmaf(m02, w2, acc[0][2][2]);
        acc[0][3][2] = fmaf(m03, w2, acc[0][3][2]);
        acc[1][0][2] = fmaf(m10, w2, acc[1][0][2]);
        acc[1][1][2] = fmaf(m11, w2, acc[1][1][2]);
        acc[1][2][2] = fmaf(m12, w2, acc[1][2][2]);
        acc[1][3][2] = fmaf(m13, w2, acc[1][3][2]);
        acc[0][0][3] = fmaf(m00, w3, acc[0][0][3]);
        acc[0][1][3] = fmaf(m01, w3, acc[0][1][3]);
        acc[0][2][3] = fmaf(m02, w3, acc[0][2][3]);
        acc[0][3][3] = fmaf(m03, w3, acc[0][3][3]);
        acc[1][0][3] = fmaf(m10, w3, acc[1][0][3]);
        acc[1][1][3] = fmaf(m11, w3, acc[1][1][3]);
        acc[1][2][3] = fmaf(m12, w3, acc[1][2][3]);
        acc[1][3][3] = fmaf(m13, w3, acc[1][3][3]);
    }

    // ---- store: relu + float4, coalesced across wt -------------------------
    #pragma unroll
    for (int r = 0; r < 2; ++r)
        #pragma unroll
        for (int oo = 0; oo < 4; ++oo) {
            float4 v;
            v.x = fmaxf(acc[r][0][oo], 0.f);
            v.y = fmaxf(acc[r][1][oo], 0.f);
            v.z = fmaxf(acc[r][2][oo], 0.f);
            v.w = fmaxf(acc[r][3][oo], 0.f);
            float* dst = out + (size_t)(n * C_ + ob + oo) * HW_
                             + (size_t)(2 * k + r) * W_ + 4 * wt;
            *(float4*)dst = v;
        }
}

extern "C" void kernel_launch(void* const* d_in, const int* in_sizes, int n_in,
                              void* d_out, int out_size, void* d_ws, size_t ws_size,
                              hipStream_t stream) {
    const float* x     = (const float*)d_in[0];
    const float* gamma = (const float*)d_in[1];
    const float* beta  = (const float*)d_in[2];
    const float* Wm    = (const float*)d_in[3];
    const float* bias  = (const float*)d_in[4];
    float* out  = (float*)d_out;
    float2* ss  = (float2*)d_ws;    // 256 x {scale, shift}

    stats_kernel<<<N_ * C_, 1024, 0, stream>>>(x, gamma, beta, ss);
    fused_kernel<<<dim3(H_ / 2, N_), 512, 0, stream>>>(x, ss, Wm, bias, out);
}

// Round 3
// 134.441 us; speedup vs baseline: 1.1580x; 1.1580x over previous
//
#include <hip/hip_runtime.h>

// Problem constants
#define N_   8
#define C_   32
#define H_   256
#define W_   256
#define HW_  (H_ * W_)

// ---------------------------------------------------------------------------
// Kernel 1: per-(n,c) instance-norm stats folded with gamma/beta into
//           scale/shift:  xn = x*scale + shift
// grid = 256 (one wg per (n,c) plane), block = 1024 (16 waves)
// ---------------------------------------------------------------------------
__global__ __launch_bounds__(1024) void stats_kernel(
    const float* __restrict__ x, const float* __restrict__ gamma,
    const float* __restrict__ beta, float2* __restrict__ ss)
{
    const int nc = blockIdx.x;      // n*32 + c
    const int t  = threadIdx.x;
    const float4* p = (const float4*)(x + (size_t)nc * HW_);

    float s0 = 0.f, s1 = 0.f, s2 = 0.f, s3 = 0.f;
    float q0 = 0.f, q1 = 0.f, q2 = 0.f, q3 = 0.f;
    #pragma unroll
    for (int i = 0; i < 16; ++i) {
        float4 v = p[t + (i << 10)];
        s0 += v.x; s1 += v.y; s2 += v.z; s3 += v.w;
        q0 = fmaf(v.x, v.x, q0); q1 = fmaf(v.y, v.y, q1);
        q2 = fmaf(v.z, v.z, q2); q3 = fmaf(v.w, v.w, q3);
    }
    double s = (double)s0 + (double)s1 + (double)s2 + (double)s3;
    double q = (double)q0 + (double)q1 + (double)q2 + (double)q3;
    #pragma unroll
    for (int off = 32; off > 0; off >>= 1) {
        s += __shfl_down(s, off);
        q += __shfl_down(q, off);
    }
    __shared__ double rs[16], rq[16];
    const int wid = t >> 6;
    if ((t & 63) == 0) { rs[wid] = s; rq[wid] = q; }
    __syncthreads();
    if (t == 0) {
        double S = 0.0, Q = 0.0;
        #pragma unroll
        for (int i = 0; i < 16; ++i) { S += rs[i]; Q += rq[i]; }
        double mean = S / (double)HW_;
        double var  = Q / (double)HW_ - mean * mean;
        double grs  = (double)gamma[nc & (C_ - 1)] / sqrt(var + 1e-5);
        float scale = (float)grs;
        float shift = (float)((double)beta[nc & (C_ - 1)] - mean * grs);
        ss[nc] = make_float2(scale, shift);
    }
}

// ---------------------------------------------------------------------------
// Kernel 2: fused  normalize -> pooled sparse field -> 1x1 conv -> relu
//
// For each 2x2 spatial pooling block (h-blocks align to even h; w-blocks
// cover {2j-1,2j}), m = max of 4 normalized values (pads = 0), s* = first
// argmax in (row,kw) order; contribution 0.75*m (m>0) or 0.25*m (m<=0,
// zeroed if s* is a pad) at s*.  out = relu(b + W * collapsed).
//
// grid = (128 h-pairs, 2 w-halves, 8 n), block = 512 (8 waves)
// Phase B: wave owns an o-octet + 64-column group; lane owns ONE column
// (both rows): per cc -> 1 val + 1 pos LDS read, 2 selects, 16 FMAs.
// ---------------------------------------------------------------------------
__global__ __launch_bounds__(512, 4) void fused_kernel(
    const float* __restrict__ x, const float2* __restrict__ ss,
    const float* __restrict__ Wm, const float* __restrict__ bias,
    float* __restrict__ out)
{
    const int k    = blockIdx.x;   // h-pair: rows 2k, 2k+1
    const int half = blockIdx.y;   // w window [128*half, 128*half+128)
    const int n    = blockIdx.z;
    const int t    = threadIdx.x;

    __shared__ float         sWT[C_][C_];  // sWT[c][o] = W[o,c]
    __shared__ float         sV[C_][66];   // block values, local jl = 0..64
    __shared__ unsigned char sP[C_][68];   // argmax pos code 0..3

    // stage W^T (Wm is [o][c] row-major)
    {
        int i = t;
        #pragma unroll
        for (int r2 = 0; r2 < 2; ++r2, i += 512) {
            int o = i >> 5, c = i & 31;
            sWT[c][o] = Wm[i];
        }
    }

    // ---- Phase A: vectorized loads + per-block max/argmax ------------------
    // thread owns 8 contiguous local cols [8*li, 8*li+8), both rows
    const int c  = t >> 4;
    const int li = t & 15;
    const float2 sc = ss[n * C_ + c];
    const float* rowb = x + (size_t)(n * C_ + c) * HW_
                          + (size_t)(2 * k) * W_ + 128 * half + 8 * li;
    float4 u00 = ((const float4*)rowb)[0];
    float4 u01 = ((const float4*)rowb)[1];
    float4 u10 = ((const float4*)(rowb + W_))[0];
    float4 u11 = ((const float4*)(rowb + W_))[1];

    // boundary column shared with the other half:
    // half0 -> w=128 (used by li==15, block jl=64 right col, real)
    // half1 -> w=127 (used by li==0,  block jl=0  left col,  real)
    float bm = 0.f; int br = 0;
    {
        bool need = (half == 0) ? (li == 15) : (li == 0);
        if (need) {
            const float* bp = x + (size_t)(n * C_ + c) * HW_
                                + (size_t)(2 * k) * W_ + (half == 0 ? 128 : 127);
            float a0 = fmaf(bp[0],  sc.x, sc.y);
            float a1 = fmaf(bp[W_], sc.x, sc.y);
            bm = fmaxf(a0, a1); br = (a1 > a0) ? 1 : 0;
        }
    }

    float vm[8];
    unsigned vr = 0;
    {
        float a0, a1;
        a0 = fmaf(u00.x, sc.x, sc.y); a1 = fmaf(u10.x, sc.x, sc.y);
        vm[0] = fmaxf(a0, a1); if (a1 > a0) vr |= 1u << 0;
        a0 = fmaf(u00.y, sc.x, sc.y); a1 = fmaf(u10.y, sc.x, sc.y);
        vm[1] = fmaxf(a0, a1); if (a1 > a0) vr |= 1u << 1;
        a0 = fmaf(u00.z, sc.x, sc.y); a1 = fmaf(u10.z, sc.x, sc.y);
        vm[2] = fmaxf(a0, a1); if (a1 > a0) vr |= 1u << 2;
        a0 = fmaf(u00.w, sc.x, sc.y); a1 = fmaf(u10.w, sc.x, sc.y);
        vm[3] = fmaxf(a0, a1); if (a1 > a0) vr |= 1u << 3;
        a0 = fmaf(u01.x, sc.x, sc.y); a1 = fmaf(u11.x, sc.x, sc.y);
        vm[4] = fmaxf(a0, a1); if (a1 > a0) vr |= 1u << 4;
        a0 = fmaf(u01.y, sc.x, sc.y); a1 = fmaf(u11.y, sc.x, sc.y);
        vm[5] = fmaxf(a0, a1); if (a1 > a0) vr |= 1u << 5;
        a0 = fmaf(u01.z, sc.x, sc.y); a1 = fmaf(u11.z, sc.x, sc.y);
        vm[6] = fmaxf(a0, a1); if (a1 > a0) vr |= 1u << 6;
        a0 = fmaf(u01.w, sc.x, sc.y); a1 = fmaf(u11.w, sc.x, sc.y);
        vm[7] = fmaxf(a0, a1); if (a1 > a0) vr |= 1u << 7;
    }

    // left straddle (local col 8*li - 1) from previous lane (same c for li>0)
    const float pvm = __shfl_up(vm[7], 1);
    const int   pvr = __shfl_up((int)((vr >> 7) & 1u), 1);

    // blocks bl = 4*li + b : left col = local 2*bl-1, right col = local 2*bl
    #pragma unroll
    for (int b = 0; b < 4; ++b) {
        float vL; int rL; bool padL = false;
        if (b == 0) {
            if (li == 0) {
                if (half == 0) { vL = 0.f; rL = 0; padL = true; }  // left spatial pad
                else           { vL = bm;  rL = br; }              // w=127, real
            } else { vL = pvm; rL = pvr; }
        } else {
            vL = vm[2 * b - 1]; rL = (int)((vr >> (2 * b - 1)) & 1u);
        }
        float vR = vm[2 * b]; int rR = (int)((vr >> (2 * b)) & 1u);
        bool chooseL = (vL > vR) || ((vL == vR) && (rL <= rR));
        float m   = chooseL ? vL : vR;
        int   p   = chooseL ? (rL << 1) : ((rR << 1) | 1);
        float val = m * (m > 0.f ? 0.75f : 0.25f);
        if (chooseL && padL) val = 0.f;
        int jl = 4 * li + b;
        sV[c][jl] = val;
        sP[c][jl] = (unsigned char)p;
    }
    if (li == 15) {   // block jl = 64: left = local col 127, right = boundary
        float vL = vm[7]; int rL = (int)((vr >> 7) & 1u);
        float vR; int rR; bool padR;
        if (half == 0) { vR = bm; rR = br; padR = false; }  // w=128, real
        else           { vR = 0.f; rR = 0; padR = true;  }  // right spatial pad
        bool chooseL = (vL > vR) || ((vL == vR) && (rL <= rR));
        float m   = chooseL ? vL : vR;
        int   p   = chooseL ? (rL << 1) : ((rR << 1) | 1);
        float val = m * (m > 0.f ? 0.75f : 0.25f);
        if (!chooseL && padR) val = 0.f;
        sV[c][64] = val;
        sP[c][64] = (unsigned char)p;
    }
    __syncthreads();

    // ---- Phase B: lane owns ONE output column (both rows), 8 out-channels --
    const int wv = t >> 6;                    // wave 0..7
    const int ob = (wv & 3) << 3;             // o-octet base
    const int L  = ((wv >> 2) << 6) + (t & 63);  // local out col 0..127
    const int jl = (L + 1) >> 1;              // block feeding this column
    const int pm0 = (L & 1) ? 0 : 2 - 1;      // row-0 match code: even L -> kw1 -> 1; odd -> 0

    float acc0[8], acc1[8];
    #pragma unroll
    for (int oo = 0; oo < 8; ++oo) {
        float bo = bias[ob + oo];
        acc0[oo] = bo; acc1[oo] = bo;
    }

    #pragma unroll 8
    for (int cc = 0; cc < C_; ++cc) {
        float v = sV[cc][jl];
        int   p = sP[cc][jl];
        float m0 = (p == pm0)     ? v : 0.f;
        float m1 = (p == pm0 + 2) ? v : 0.f;
        float4 wa = *(const float4*)&sWT[cc][ob];
        float4 wb = *(const float4*)&sWT[cc][ob + 4];
        acc0[0] = fmaf(m0, wa.x, acc0[0]);
        acc0[1] = fmaf(m0, wa.y, acc0[1]);
        acc0[2] = fmaf(m0, wa.z, acc0[2]);
        acc0[3] = fmaf(m0, wa.w, acc0[3]);
        acc0[4] = fmaf(m0, wb.x, acc0[4]);
        acc0[5] = fmaf(m0, wb.y, acc0[5]);
        acc0[6] = fmaf(m0, wb.z, acc0[6]);
        acc0[7] = fmaf(m0, wb.w, acc0[7]);
        acc1[0] = fmaf(m1, wa.x, acc1[0]);
        acc1[1] = fmaf(m1, wa.y, acc1[1]);
        acc1[2] = fmaf(m1, wa.z, acc1[2]);
        acc1[3] = fmaf(m1, wa.w, acc1[3]);
        acc1[4] = fmaf(m1, wb.x, acc1[4]);
        acc1[5] = fmaf(m1, wb.y, acc1[5]);
        acc1[6] = fmaf(m1, wb.z, acc1[6]);
        acc1[7] = fmaf(m1, wb.w, acc1[7]);
    }

    // ---- store: relu, lanes consecutive in w -> coalesced ------------------
    float* obase = out + (size_t)(n * C_ + ob) * HW_
                       + (size_t)(2 * k) * W_ + 128 * half + L;
    #pragma unroll
    for (int oo = 0; oo < 8; ++oo) {
        obase[(size_t)oo * HW_]      = fmaxf(acc0[oo], 0.f);
        obase[(size_t)oo * HW_ + W_] = fmaxf(acc1[oo], 0.f);
    }
}

extern "C" void kernel_launch(void* const* d_in, const int* in_sizes, int n_in,
                              void* d_out, int out_size, void* d_ws, size_t ws_size,
                              hipStream_t stream) {
    const float* x     = (const float*)d_in[0];
    const float* gamma = (const float*)d_in[1];
    const float* beta  = (const float*)d_in[2];
    const float* Wm    = (const float*)d_in[3];
    const float* bias  = (const float*)d_in[4];
    float* out  = (float*)d_out;
    float2* ss  = (float2*)d_ws;    // 256 x {scale, shift}

    stats_kernel<<<N_ * C_, 1024, 0, stream>>>(x, gamma, beta, ss);
    fused_kernel<<<dim3(H_ / 2, 2, N_), 512, 0, stream>>>(x, ss, Wm, bias, out);
}